// Round 10
// baseline (247.676 us; speedup 1.0000x reference)
//
#include <hip/hip_runtime.h>

#define B_  8
#define IB_ 1024
#define S_  4096
#define D_  512

typedef _Float16 f16;
typedef _Float16 f16x8 __attribute__((ext_vector_type(8)));
typedef _Float16 f16x4 __attribute__((ext_vector_type(4)));
typedef float    f32x4 __attribute__((ext_vector_type(4)));

// ---------------- async global->LDS, 16B per lane ----------------
__device__ __forceinline__ void gld_lds16(const f16* g, f16* l) {
  __builtin_amdgcn_global_load_lds(
      (const __attribute__((address_space(1))) void*)g,
      (__attribute__((address_space(3))) void*)l, 16, 0, 0);
}

// ---------------- generic C = A(M,K) * B(N,K)^T  (f16 in, f32 accum) -------
// PROVEN r2-r9. 128x128 tile, BK=32, 4 waves, 2-phase prefetch (dbuf LDS,
// counted vmcnt). ksplit>1: grid.z = batch*ksplit, slice stores partials
// (f32 via C32 or f16 via C16) to C + blockIdx.z*sCb; reducer sums slices.
__global__ __launch_bounds__(256) void gemm_bt(
    const f16* __restrict__ A, const f16* __restrict__ B,
    float* __restrict__ C32, f16* __restrict__ C16,
    int M, int N, int K, int lda, int ldb, int ksplit,
    long long sAb, long long sBb, long long sCb,
    const float* __restrict__ bias_row, const float* __restrict__ bias_col,
    float scale)
{
  __shared__ f16 ldsA[2][128 * 32];
  __shared__ f16 ldsB[2][128 * 32];
  const int tid  = threadIdx.x;
  const int lane = tid & 63;
  const int wave = tid >> 6;
  const int zb   = blockIdx.z / ksplit;
  const int ks   = blockIdx.z % ksplit;
  A += (size_t)zb * (size_t)sAb;
  B += (size_t)zb * (size_t)sBb;
  const int m0 = blockIdx.y * 128;
  const int n0 = blockIdx.x * 128;
  const int wm = wave >> 1, wn = wave & 1;

  f32x4 acc[4][4];
#pragma unroll
  for (int i = 0; i < 4; ++i)
#pragma unroll
    for (int j = 0; j < 4; ++j) acc[i][j] = (f32x4){0.f, 0.f, 0.f, 0.f};

  int aoff[4], boff[4];
  const int cl = lane >> 4;
#pragma unroll
  for (int r = 0; r < 4; ++r) {
    int rowa = wm * 64 + r * 16 + (lane & 15);
    aoff[r] = rowa * 32 + (cl ^ ((rowa >> 1) & 3)) * 8;
    int rowb = wn * 64 + r * 16 + (lane & 15);
    boff[r] = rowb * 32 + (cl ^ ((rowb >> 1) & 3)) * 8;
  }
  int srow[2], scg[2];
#pragma unroll
  for (int it = 0; it < 2; ++it) {
    int ch = wave * 64 + it * 256 + lane;
    srow[it] = ch >> 2;
    scg[it]  = (ch & 3) ^ ((srow[it] >> 1) & 3);
  }

#define STAGE(bf_, k0_)                                                        \
  do {                                                                         \
    _Pragma("unroll")                                                          \
    for (int it = 0; it < 2; ++it) {                                           \
      gld_lds16(A + (size_t)(m0 + srow[it]) * (size_t)lda +                    \
                    ((k0_) + scg[it] * 8),                                     \
                &ldsA[bf_][(wave * 64 + it * 256) * 8]);                       \
      gld_lds16(B + (size_t)(n0 + srow[it]) * (size_t)ldb +                    \
                    ((k0_) + scg[it] * 8),                                     \
                &ldsB[bf_][(wave * 64 + it * 256) * 8]);                       \
    }                                                                          \
  } while (0)

  const int Kc   = K / ksplit;
  const int kbeg = ks * Kc;
  const int nt   = Kc / 32;

  STAGE(0, kbeg);
  for (int t = 0; t < nt; ++t) {
    const int cur = t & 1;
    if (t + 1 < nt) {
      STAGE(cur ^ 1, kbeg + (t + 1) * 32);
      asm volatile("s_waitcnt vmcnt(4)" ::: "memory");
    } else {
      asm volatile("s_waitcnt vmcnt(0)" ::: "memory");
    }
    __builtin_amdgcn_s_barrier();
    __builtin_amdgcn_sched_barrier(0);
    f16x8 af[4], bf[4];
#pragma unroll
    for (int r = 0; r < 4; ++r) af[r] = *(const f16x8*)&ldsA[cur][aoff[r]];
#pragma unroll
    for (int r = 0; r < 4; ++r) bf[r] = *(const f16x8*)&ldsB[cur][boff[r]];
#pragma unroll
    for (int mr = 0; mr < 4; ++mr)
#pragma unroll
      for (int nr = 0; nr < 4; ++nr)
        acc[mr][nr] = __builtin_amdgcn_mfma_f32_16x16x32_f16(
            af[mr], bf[nr], acc[mr][nr], 0, 0, 0);
    __builtin_amdgcn_sched_barrier(0);
    __builtin_amdgcn_s_barrier();
    __builtin_amdgcn_sched_barrier(0);
  }
#undef STAGE

  const size_t cz = (ksplit > 1) ? (size_t)blockIdx.z : (size_t)zb;
  float* c32 = C32 ? C32 + cz * (size_t)sCb : nullptr;
  f16*   c16 = C16 ? C16 + cz * (size_t)sCb : nullptr;
#pragma unroll
  for (int mr = 0; mr < 4; ++mr) {
#pragma unroll
    for (int r = 0; r < 4; ++r) {
      int grow = m0 + wm * 64 + mr * 16 + (lane >> 4) * 4 + r;
      float brv = bias_row ? bias_row[grow] : 0.f;
#pragma unroll
      for (int nr = 0; nr < 4; ++nr) {
        int gcol = n0 + wn * 64 + nr * 16 + (lane & 15);
        float v = acc[mr][nr][r] * scale + brv +
                  (bias_col ? bias_col[gcol] : 0.f);
        if (c32) c32[(size_t)grow * N + gcol] = v;
        else     c16[(size_t)grow * N + gcol] = (f16)v;
      }
    }
  }
}

// ---------------- fused-P GEMM v3: pt = softmax-rank1 @ textT^T ------------
// Tile 64m x 512n (full D): zero synthesis duplication, 32 MFMA/K-step/wave
// (2x v2 -> amortizes the 2-barrier skeleton). 4 waves, each 64m x 128n
// (acc[4][8]). LDS: A 4KB (synth once/block) + B dbuf 64KB + consts 8KB
// = 76KB -> 2 blocks/CU; grid 512 = exact residency. Split-K=4, f16
// partials. XCD swizzle: one batch per XCD (textT_b ~ 4MB L2).
__global__ __launch_bounds__(256) void gemm_pt(
    const f16* __restrict__ Bt, const float* __restrict__ uarr,
    const float* __restrict__ inv2, const float* __restrict__ Acs,
    const float* __restrict__ bb2s, f16* __restrict__ parts)
{
  __shared__ f16 ldsA[64 * 32];            // 4 KB
  __shared__ f16 ldsB[2][512 * 32];        // 64 KB dbuf
  __shared__ float cA2[1024], cB2[1024];   // 8 KB, consts * log2(e)
  const int tid  = threadIdx.x;
  const int lane = tid & 63;
  const int wave = tid >> 6;
  // swizzle: 512 blocks -> 64 contiguous per XCD = one batch
  int id = (int)blockIdx.x;
  id = (id & 7) * 64 + (id >> 3);
  const int zb  = id >> 6;
  const int rem = id & 63;
  const int mt  = rem >> 2;                // 16 m-tiles of 64 rows
  const int ks  = rem & 3;                 // 4 K-chunks of 1024
  const int kbeg = ks * 1024;
  const int m0 = mt * 64;
  const f16* B = Bt + (size_t)zb * ((size_t)D_ * S_);

  const float L2E = 1.44269504088896340736f;
  for (int i = tid; i < 1024; i += 256) {
    cA2[i] = Acs[kbeg + i] * L2E;
    cB2[i] = bb2s[kbeg + i] * L2E;
  }
  // synthesis assignment: thread -> (row = tid>>2, k-chunk = tid&3)
  const int srowA = tid >> 2;
  const int scgA  = tid & 3;
  const int spcA  = scgA ^ ((srowA >> 1) & 3);
  const float u_  = uarr[zb * IB_ + m0 + srowA];
  const float iv_ = inv2[zb * IB_ + m0 + srowA];
  // fragment read offsets
  const int cl = lane >> 4;
  int aoff[4], boff[8];
#pragma unroll
  for (int r = 0; r < 4; ++r) {
    int rowa = r * 16 + (lane & 15);       // all waves read same A rows
    aoff[r] = rowa * 32 + (cl ^ ((rowa >> 1) & 3)) * 8;
  }
#pragma unroll
  for (int r = 0; r < 8; ++r) {
    int rowb = wave * 128 + r * 16 + (lane & 15);
    boff[r] = rowb * 32 + (cl ^ ((rowb >> 1) & 3)) * 8;
  }
  // B staging coords: 2048 chunks of 16B, 8 per thread
  int srow[8], scg[8];
#pragma unroll
  for (int it = 0; it < 8; ++it) {
    int ch = it * 256 + tid;
    srow[it] = ch >> 2;
    scg[it]  = (ch & 3) ^ ((srow[it] >> 1) & 3);
  }
  f32x4 acc[4][8];
#pragma unroll
  for (int i = 0; i < 4; ++i)
#pragma unroll
    for (int j = 0; j < 8; ++j) acc[i][j] = (f32x4){0.f, 0.f, 0.f, 0.f};

#define STAGEB(bf_, k0_)                                                       \
  do {                                                                         \
    _Pragma("unroll")                                                          \
    for (int it = 0; it < 8; ++it) {                                           \
      gld_lds16(B + (size_t)srow[it] * (size_t)S_ + ((k0_) + scg[it] * 8),     \
                &ldsB[bf_][(it * 256 + tid) * 8]);                             \
    }                                                                          \
  } while (0)

  __syncthreads();                 // cA2/cB2 visible
  STAGEB(0, kbeg);
  for (int t = 0; t < 32; ++t) {
    const int cur = t & 1;
    if (t + 1 < 32) STAGEB(cur ^ 1, kbeg + (t + 1) * 32);
    // ---- cooperative A synthesis: 8 P values/thread, once per block ----
    {
      const int kl = t * 32 + scgA * 8;
      f16x8 hp;
#pragma unroll
      for (int j = 0; j < 8; ++j) {
        float e = exp2f(fmaf(u_, cA2[kl + j], cB2[kl + j])) * iv_;
        hp[j] = (f16)e;
      }
      *(f16x8*)&ldsA[srowA * 32 + spcA * 8] = hp;
    }
    asm volatile("s_waitcnt lgkmcnt(0)" ::: "memory");  // A write done
    __builtin_amdgcn_sched_barrier(0);
    if (t + 1 < 32) asm volatile("s_waitcnt vmcnt(8)" ::: "memory");
    else            asm volatile("s_waitcnt vmcnt(0)" ::: "memory");
    __builtin_amdgcn_s_barrier();
    __builtin_amdgcn_sched_barrier(0);
    f16x8 af[4], bf[8];
#pragma unroll
    for (int r = 0; r < 4; ++r) af[r] = *(const f16x8*)&ldsA[aoff[r]];
#pragma unroll
    for (int r = 0; r < 8; ++r) bf[r] = *(const f16x8*)&ldsB[cur][boff[r]];
    asm volatile("s_waitcnt lgkmcnt(0)" ::: "memory");
    __builtin_amdgcn_sched_barrier(0);
#pragma unroll
    for (int mr = 0; mr < 4; ++mr)
#pragma unroll
      for (int nr = 0; nr < 8; ++nr)
        acc[mr][nr] = __builtin_amdgcn_mfma_f32_16x16x32_f16(
            af[mr], bf[nr], acc[mr][nr], 0, 0, 0);
    __builtin_amdgcn_sched_barrier(0);
    __builtin_amdgcn_s_barrier();   // readers done before next overwrite
    __builtin_amdgcn_sched_barrier(0);
  }
#undef STAGEB

  f16* cp = parts + (size_t)(zb * 4 + ks) * (size_t)(IB_ * D_);
#pragma unroll
  for (int mr = 0; mr < 4; ++mr) {
#pragma unroll
    for (int rr = 0; rr < 4; ++rr) {
      int grow = m0 + mr * 16 + (lane >> 4) * 4 + rr;
#pragma unroll
      for (int nr = 0; nr < 8; ++nr) {
        int gcol = wave * 128 + nr * 16 + (lane & 15);
        cp[(size_t)grow * D_ + gcol] = (f16)acc[mr][nr][rr];
      }
    }
  }
}

// ---------------- reduce 4 f16 split-K slices: [B][4][ID] -> [B][ID] ------
__global__ __launch_bounds__(256) void reduce_ks4_f16(
    const f16x8* __restrict__ p, f16x8* __restrict__ o, unsigned n8)
{
  const unsigned pb8 = (IB_ * D_) / 8;   // 65536 f16x8 units per slice
  unsigned i = blockIdx.x * 256u + threadIdx.x;
  const unsigned stride = gridDim.x * 256u;
  for (; i < n8; i += stride) {
    unsigned g = i / pb8, r = i - g * pb8;
    size_t base = ((size_t)g * 4u) * pb8 + r;
    float acc[8] = {0.f, 0.f, 0.f, 0.f, 0.f, 0.f, 0.f, 0.f};
#pragma unroll
    for (int ks = 0; ks < 4; ++ks) {
      f16x8 v = p[base + (size_t)ks * pb8];
#pragma unroll
      for (int j = 0; j < 8; ++j) acc[j] += (float)v[j];
    }
    f16x8 h;
#pragma unroll
    for (int j = 0; j < 8; ++j) h[j] = (f16)acc[j];
    o[i] = h;
  }
}

// ---------------- reduce 2 f16 slices + col bias -> f32 out ---------------
__global__ __launch_bounds__(256) void reduce_ks2_bias(
    const f16x8* __restrict__ p, const float* __restrict__ bias,
    float4* __restrict__ o, unsigned n8)
{
  unsigned i = blockIdx.x * 256u + threadIdx.x;
  const unsigned stride = gridDim.x * 256u;
  for (; i < n8; i += stride) {
    f16x8 a = p[i];
    f16x8 b = p[i + (size_t)n8];
    const int c0 = (int)((i * 8u) & (D_ - 1));
    float4 lo, hi;
    lo.x = (float)a[0] + (float)b[0] + bias[c0 + 0];
    lo.y = (float)a[1] + (float)b[1] + bias[c0 + 1];
    lo.z = (float)a[2] + (float)b[2] + bias[c0 + 2];
    lo.w = (float)a[3] + (float)b[3] + bias[c0 + 3];
    hi.x = (float)a[4] + (float)b[4] + bias[c0 + 4];
    hi.y = (float)a[5] + (float)b[5] + bias[c0 + 5];
    hi.z = (float)a[6] + (float)b[6] + bias[c0 + 6];
    hi.w = (float)a[7] + (float)b[7] + bias[c0 + 7];
    o[(size_t)i * 2]     = lo;
    o[(size_t)i * 2 + 1] = hi;
  }
}

// ---------------- f32 -> f16 ----------------
__global__ __launch_bounds__(256) void cvt_f32_to_f16(
    const float* __restrict__ in, f16* __restrict__ out, unsigned n)
{
  unsigned i = (blockIdx.x * 256u + threadIdx.x) * 4u;
  if (i >= n) return;
  const float4 v = *(const float4*)(in + i);
  f16x4 h;
  h[0] = (f16)v.x; h[1] = (f16)v.y; h[2] = (f16)v.z; h[3] = (f16)v.w;
  *(f16x4*)(out + i) = h;
}

// ---------------- text (B,S,D) f32 -> textT (B,D,S) f16 ------------------
__global__ __launch_bounds__(256) void transpose_text(
    const float* __restrict__ in, f16* __restrict__ out)
{
  __shared__ float t[32][65];
  const int b = blockIdx.z;
  const int s0 = blockIdx.x * 64, d0 = blockIdx.y * 32;
  const int dx = threadIdx.x & 31;
  const int sy = threadIdx.x >> 5;
  const float* ip = in + ((size_t)b * S_ + s0) * D_ + d0;
#pragma unroll
  for (int j = 0; j < 8; ++j) {
    int sl = j * 8 + sy;
    t[dx][sl] = ip[(size_t)sl * D_ + dx];
  }
  __syncthreads();
  const int sx = threadIdx.x & 63;
  const int dy = threadIdx.x >> 6;
  f16* op = out + ((size_t)b * D_ + d0) * S_ + s0;
#pragma unroll
  for (int j = 0; j < 8; ++j) {
    int dl = j * 4 + dy;
    op[(size_t)dl * S_ + sx] = (f16)t[dl][sx];
  }
}

// ---------------- row sums of Wb2s (S, IB): Acs[s] = sum_j W[s,j] --------
__global__ __launch_bounds__(256) void rowsum_kernel(
    const float* __restrict__ W, float* __restrict__ out)
{
  int s = blockIdx.x;
  const float* row = W + (size_t)s * IB_;
  float acc = 0.f;
  for (int j = threadIdx.x; j < IB_; j += 256) acc += row[j];
  __shared__ float red[4];
#pragma unroll
  for (int o = 32; o >= 1; o >>= 1) acc += __shfl_xor(acc, o);
  if ((threadIdx.x & 63) == 0) red[threadIdx.x >> 6] = acc;
  __syncthreads();
  if (threadIdx.x == 0) out[s] = red[0] + red[1] + red[2] + red[3];
}

// ---------------- mu = alpha*Acs + bb2s, top-2050 mask, r̂ -----------------
__device__ __forceinline__ unsigned fkey(float x) {
  unsigned u = __float_as_uint(x);
  return (u & 0x80000000u) ? ~u : (u | 0x80000000u);
}

__global__ __launch_bounds__(256) void prep_mu(
    const float* __restrict__ Acs, const float* __restrict__ bb2s,
    float* __restrict__ muk, float* __restrict__ rhat)
{
  __shared__ float vals[S_];
  __shared__ unsigned hist[256];
  __shared__ unsigned sprefix;
  __shared__ int srem;
  __shared__ float rred[4];
  const float e1 = 2.71828182845904523536f;
  const float Z = 3.f * e1 + (float)(IB_ - 3);   // interior-row normalizer
  const float alpha = 1.f / Z;
  for (int s = threadIdx.x; s < S_; s += 256)
    vals[s] = alpha * Acs[s] + bb2s[s];
  if (threadIdx.x == 0) { sprefix = 0u; srem = S_ / 2 + 2; }  // 2050
  __syncthreads();
  for (int shift = 24; shift >= 0; shift -= 8) {
    hist[threadIdx.x] = 0u;
    __syncthreads();
    unsigned pfx = sprefix;
    unsigned himask = (shift == 24) ? 0u : (0xFFFFFFFFu << (shift + 8));
    for (int s = threadIdx.x; s < S_; s += 256) {
      unsigned key = fkey(vals[s]);
      if ((key & himask) == (pfx & himask))
        atomicAdd(&hist[(key >> shift) & 255u], 1u);
    }
    __syncthreads();
    if (threadIdx.x == 0) {
      int rem = srem;
      unsigned acc = 0;
      int b = 255;
      for (; b > 0; --b) {
        unsigned c = hist[b];
        if (acc + c >= (unsigned)rem) break;
        acc += c;
      }
      sprefix = pfx | ((unsigned)b << shift);
      srem = rem - (int)acc;
    }
    __syncthreads();
  }
  const unsigned T = sprefix;
  float myrs = 0.f;
  for (int s = threadIdx.x; s < S_; s += 256) {
    float v = vals[s];
    bool keep = fkey(v) >= T;
    muk[s] = keep ? v : 0.f;
    if (keep) myrs += v;
  }
#pragma unroll
  for (int o = 32; o >= 1; o >>= 1) myrs += __shfl_xor(myrs, o);
  if ((threadIdx.x & 63) == 0) rred[threadIdx.x >> 6] = myrs;
  __syncthreads();
  if (threadIdx.x == 0) rhat[0] = rred[0] + rred[1] + rred[2] + rred[3];
}

// ---------------- t̂ partials: tp[b][c][d] = sum_{s in chunk c} muk[s]*text -
__global__ __launch_bounds__(256) void that_partial(
    const float* __restrict__ text, const float* __restrict__ muk,
    float* __restrict__ tp)
{
  const int d = blockIdx.x * 256 + threadIdx.x;   // gridDim.x = 2
  const int c = blockIdx.y;                        // 32 chunks of 128 rows
  const int b = blockIdx.z;
  const float* tb = text + ((size_t)b * S_ + (size_t)c * 128) * D_ + d;
  float acc = 0.f;
  for (int s = 0; s < 128; ++s) {
    float m = muk[c * 128 + s];        // wave-uniform -> skips whole row load
    if (m != 0.f) acc += m * tb[(size_t)s * D_];
  }
  tp[((size_t)b * 32 + c) * D_ + d] = acc;
}

// ---------------- tt[b][d] = sum_c tp[b][c][d] ---------------------------
__global__ __launch_bounds__(256) void tt_reduce(
    const float* __restrict__ tp, float* __restrict__ tt)
{
  const int d = blockIdx.x * 256 + threadIdx.x;   // gridDim.x = 2
  const int b = blockIdx.y;                        // gridDim.y = 8
  float acc = 0.f;
#pragma unroll
  for (int c = 0; c < 32; ++c) acc += tp[((size_t)b * 32 + c) * D_ + d];
  tt[(size_t)b * D_ + d] = acc;
}

// ---------------- m̂[b][r] = Wk[r,:].tt[b] + bk[r]*r̂ ; grid = 512 rows ----
__global__ __launch_bounds__(256) void mhat2_kernel(
    const float* __restrict__ tt, const float* __restrict__ Wk,
    const float* __restrict__ bk, const float* __restrict__ rhat,
    float* __restrict__ mh)
{
  __shared__ float tl[B_ * D_];        // 16 KB: all batches' t̂
  const int t = threadIdx.x;
  for (int i = t; i < B_ * D_; i += 256) tl[i] = tt[i];
  __syncthreads();
  const int r = blockIdx.x;
  const int lane = t & 63, wave = t >> 6;
  const float* wr = Wk + (size_t)r * D_;
  float w[8];
#pragma unroll
  for (int j = 0; j < 8; ++j) w[j] = wr[lane + 64 * j];
  const float bkr = bk[r] * rhat[0];
#pragma unroll
  for (int bb = 0; bb < 2; ++bb) {
    const int b = wave * 2 + bb;
    float acc = 0.f;
#pragma unroll
    for (int j = 0; j < 8; ++j) acc += w[j] * tl[b * D_ + lane + 64 * j];
#pragma unroll
    for (int o = 32; o >= 1; o >>= 1) acc += __shfl_xor(acc, o);
    if (lane == 0) mh[b * D_ + r] = acc + bkr;
  }
}

// ---------------- ypart[c][b][d] = sum_{r in chunk c} Wq[r,d]*mh[b][r] ----
__global__ __launch_bounds__(256) void ypart_kernel(
    const float* __restrict__ Wq, const float* __restrict__ mh,
    float* __restrict__ yp)
{
  __shared__ float ms[B_ * 64];        // mh slice: 8 batches x 64 rows
  const int t = threadIdx.x;
  const int d = blockIdx.x * 256 + t;  // gridDim.x = 2
  const int c = blockIdx.y;            // gridDim.y = 8 chunks of 64 rows
  for (int i = t; i < B_ * 64; i += 256) {
    int b = i >> 6, rr = i & 63;
    ms[i] = mh[b * D_ + c * 64 + rr];
  }
  __syncthreads();
  float acc[8] = {0.f, 0.f, 0.f, 0.f, 0.f, 0.f, 0.f, 0.f};
  for (int rr = 0; rr < 64; ++rr) {
    float wv = Wq[(size_t)(c * 64 + rr) * D_ + d];
#pragma unroll
    for (int b = 0; b < 8; ++b) acc[b] += wv * ms[b * 64 + rr];
  }
#pragma unroll
  for (int b = 0; b < 8; ++b)
    yp[((size_t)c * 8 + b) * D_ + d] = acc[b];
}

// ---------------- y[b][d] = sum_c ypart[c][b][d] -------------------------
__global__ __launch_bounds__(256) void yred_kernel(
    const float* __restrict__ yp, float* __restrict__ y)
{
  const int d = blockIdx.x * 256 + threadIdx.x;   // gridDim.x = 2
  const int b = blockIdx.y;                        // gridDim.y = 8
  float acc = 0.f;
#pragma unroll
  for (int c = 0; c < 8; ++c) acc += yp[((size_t)c * 8 + b) * D_ + d];
  y[(size_t)b * D_ + d] = acc;
}

// ---------------- cb[b] = bq . mh[b] -------------------------------------
__global__ __launch_bounds__(256) void cb_kernel(
    const float* __restrict__ bq, const float* __restrict__ mh,
    float* __restrict__ cb)
{
  const int lane = threadIdx.x & 63, wave = threadIdx.x >> 6;
#pragma unroll
  for (int bb = 0; bb < 2; ++bb) {
    const int b = wave * 2 + bb;
    float acc = 0.f;
#pragma unroll
    for (int j = 0; j < 8; ++j) {
      int k = lane + 64 * j;
      acc += bq[k] * mh[b * D_ + k];
    }
#pragma unroll
    for (int o = 32; o >= 1; o >>= 1) acc += __shfl_xor(acc, o);
    if (lane == 0) cb[b] = acc;
  }
}

// ---------------- fused u + softmax stats per row -------------------------
// u[row] = (img_row . y_b + cb[b]) * scl ; inv2[row] = exp(-mx)/Z
__global__ __launch_bounds__(256) void upstat_kernel(
    const float* __restrict__ img, const float* __restrict__ y,
    const float* __restrict__ cbv, const float* __restrict__ Acs,
    const float* __restrict__ bb2s, float scl,
    float* __restrict__ uo, float* __restrict__ inv2)
{
  const int row = blockIdx.x;
  const int b = row >> 10;
  const int t = threadIdx.x;
  __shared__ float red[4];
  __shared__ float ubc;
  const float* ir = img + (size_t)row * D_;
  const float* yb = y + (size_t)b * D_;
  float du = ir[t] * yb[t] + ir[t + 256] * yb[t + 256];
#pragma unroll
  for (int o = 32; o >= 1; o >>= 1) du += __shfl_xor(du, o);
  if ((t & 63) == 0) red[t >> 6] = du;
  __syncthreads();
  if (t == 0) {
    float uu = (red[0] + red[1] + red[2] + red[3] + cbv[b]) * scl;
    ubc = uu;
    uo[row] = uu;
  }
  __syncthreads();
  const float u = ubc;
  float v[16];
  float mx = -3.4e38f;
#pragma unroll
  for (int j = 0; j < 16; ++j) {
    int s = t + 256 * j;
    v[j] = fmaf(u, Acs[s], bb2s[s]);
    mx = fmaxf(mx, v[j]);
  }
#pragma unroll
  for (int o = 32; o >= 1; o >>= 1) mx = fmaxf(mx, __shfl_xor(mx, o));
  if ((t & 63) == 0) red[t >> 6] = mx;
  __syncthreads();
  mx = fmaxf(fmaxf(red[0], red[1]), fmaxf(red[2], red[3]));
  __syncthreads();
  float sum = 0.f;
#pragma unroll
  for (int j = 0; j < 16; ++j) sum += __expf(v[j] - mx);
#pragma unroll
  for (int o = 32; o >= 1; o >>= 1) sum += __shfl_xor(sum, o);
  if ((t & 63) == 0) red[t >> 6] = sum;
  __syncthreads();
  if (t == 0) {
    float Zs = red[0] + red[1] + red[2] + red[3];
    inv2[row] = __expf(-mx) / Zs;
  }
}

// =========================================================================
extern "C" void kernel_launch(void* const* d_in, const int* in_sizes, int n_in,
                              void* d_out, int out_size, void* d_ws, size_t ws_size,
                              hipStream_t stream)
{
  const float* text = (const float*)d_in[0];   // (B,S,D)
  const float* img  = (const float*)d_in[1];   // (B,IB,D)
  const float* Wq   = (const float*)d_in[2];
  const float* bq   = (const float*)d_in[3];
  const float* Wk   = (const float*)d_in[4];
  const float* bk   = (const float*)d_in[5];
  const float* Wv   = (const float*)d_in[6];
  const float* bv   = (const float*)d_in[7];
  const float* Wb2s = (const float*)d_in[8];   // (S,IB)
  const float* bb2s = (const float*)d_in[9];   // (S,)
  float* outp = (float*)d_out;
  char* ws = (char*)d_ws;

  const long long ID = (long long)IB_ * D_;    // 2^19
  const size_t MB = 1048576ull;

  // ws layout (NEED = 96 MiB; >=200 MiB proved available in round 2):
  //  [  0, 32)  textT f16 (B,D,S)
  //  [ 32, 40)  pt16 f16
  //  [ 40, 72)  parts_pt f16, 4 slices x 8 MB
  //  [ 72, 88)  parts_out f16, 2 slices x 8 MB
  //  [ 88, 89)  wv16
  //  [ 89, ..)  smalls
  const size_t NEED = 96 * MB;
  if (ws_size < NEED) return;

  f16*   textT   = (f16*)(ws + 0);
  f16*   pt16    = (f16*)(ws + 32 * MB);
  f16*   partsPT = (f16*)(ws + 40 * MB);
  f16*   partsO  = (f16*)(ws + 72 * MB);
  f16*   wv16    = (f16*)(ws + 88 * MB);
  const size_t SB = 89 * MB;
  float* Acs  = (float*)(ws + SB);
  float* muk  = (float*)(ws + SB + 16384);
  float* tp   = (float*)(ws + SB + 32768);        // 512 KB
  float* tt   = (float*)(ws + SB + 557056);
  float* mh   = (float*)(ws + SB + 573440);
  float* rhat = (float*)(ws + SB + 589824);
  float* yp   = (float*)(ws + SB + 593920);       // 128 KB
  float* y    = (float*)(ws + SB + 724992);
  float* cb   = (float*)(ws + SB + 741376);
  float* u    = (float*)(ws + SB + 745472);       // 32 KB
  float* inv2 = (float*)(ws + SB + 778240);       // 32 KB

  dim3 blk(256);
  const float scl = 0.04419417382415922f;  // 1/sqrt(512)

  // 1) Acs = rowsum(Wb2s); mu + top-2050 mask + r̂
  rowsum_kernel<<<S_, blk, 0, stream>>>(Wb2s, Acs);
  prep_mu<<<1, blk, 0, stream>>>(Acs, bb2s, muk, rhat);
  // 2) t̂ = muk-weighted row-sum of text
  that_partial<<<dim3(2, 32, B_), blk, 0, stream>>>(text, muk, tp);
  tt_reduce<<<dim3(2, B_), blk, 0, stream>>>(tp, tt);
  // 3) m̂_b = Wk @ t̂_b + bk*r̂
  mhat2_kernel<<<512, blk, 0, stream>>>(tt, Wk, bk, rhat, mh);
  // 4) y_b = Wq^T @ m̂_b ; cb_b = bq . m̂_b
  ypart_kernel<<<dim3(2, 8), blk, 0, stream>>>(Wq, mh, yp);
  yred_kernel<<<dim3(2, B_), blk, 0, stream>>>(yp, y);
  cb_kernel<<<1, blk, 0, stream>>>(bq, mh, cb);
  // 5) u + softmax stats fused (P never materialized)
  upstat_kernel<<<B_ * IB_, blk, 0, stream>>>(img, y, cb, Acs, bb2s, scl,
                                              u, inv2);
  // 6) textT (B,D,S) f16 — PV GEMM operand
  transpose_text<<<dim3(S_/64, D_/32, B_), blk, 0, stream>>>(text, textT);
  // 7) pt_b = P_b @ text_b, P synthesized cooperatively; 64x512 tile, KS=4
  gemm_pt<<<512, blk, 0, stream>>>(textT, u, inv2, Acs, bb2s, partsPT);
  // 8) reduce 4 slices -> pt16 f16
  reduce_ks4_f16<<<1024, blk, 0, stream>>>(
      (const f16x8*)partsPT, (f16x8*)pt16, (unsigned)((B_ * ID) / 8));
  // 9) Wv -> f16
  cvt_f32_to_f16<<<(D_*D_)/1024, blk, 0, stream>>>(Wv, wv16, D_*D_);
  // 10) out = pt @ Wv^T (+bv at reduce) : split-K=2, f16 partials
  gemm_bt<<<dim3(D_/128, (B_*IB_)/128, 2), blk, 0, stream>>>(
      pt16, wv16, nullptr, partsO, B_*IB_, D_, D_, D_, D_, 2,
      0, 0, (long long)B_ * ID, nullptr, nullptr, 1.f);
  // 11) reduce 2 slices + bv -> d_out f32 (softmax rows sum to 1, so
  //     P @ bv-broadcast == bv exactly)
  reduce_ks2_bias<<<1024, blk, 0, stream>>>(
      (const f16x8*)partsO, bv, (float4*)outp, (unsigned)((B_ * ID) / 8));
}

// Round 11
// 194.287 us; speedup vs baseline: 1.2748x; 1.2748x over previous
//
#include <hip/hip_runtime.h>

#define B_  8
#define IB_ 1024
#define S_  4096
#define D_  512

typedef _Float16 f16;
typedef _Float16 f16x8 __attribute__((ext_vector_type(8)));
typedef _Float16 f16x4 __attribute__((ext_vector_type(4)));
typedef float    f32x4 __attribute__((ext_vector_type(4)));

// ---------------- async global->LDS, 16B per lane ----------------
__device__ __forceinline__ void gld_lds16(const f16* g, f16* l) {
  __builtin_amdgcn_global_load_lds(
      (const __attribute__((address_space(1))) void*)g,
      (__attribute__((address_space(3))) void*)l, 16, 0, 0);
}

// ---------------- generic C = A(M,K) * B(N,K)^T  (f16 in, f32 accum) -------
// PROVEN r2-r10. 128x128 tile, BK=32, 4 waves, 2-phase prefetch (dbuf LDS,
// counted vmcnt). ksplit>1: grid.z = batch*ksplit, slice stores partials
// (f32 via C32 or f16 via C16) to C + blockIdx.z*sCb; reducer sums slices.
__global__ __launch_bounds__(256) void gemm_bt(
    const f16* __restrict__ A, const f16* __restrict__ B,
    float* __restrict__ C32, f16* __restrict__ C16,
    int M, int N, int K, int lda, int ldb, int ksplit,
    long long sAb, long long sBb, long long sCb,
    const float* __restrict__ bias_row, const float* __restrict__ bias_col,
    float scale)
{
  __shared__ f16 ldsA[2][128 * 32];
  __shared__ f16 ldsB[2][128 * 32];
  const int tid  = threadIdx.x;
  const int lane = tid & 63;
  const int wave = tid >> 6;
  const int zb   = blockIdx.z / ksplit;
  const int ks   = blockIdx.z % ksplit;
  A += (size_t)zb * (size_t)sAb;
  B += (size_t)zb * (size_t)sBb;
  const int m0 = blockIdx.y * 128;
  const int n0 = blockIdx.x * 128;
  const int wm = wave >> 1, wn = wave & 1;

  f32x4 acc[4][4];
#pragma unroll
  for (int i = 0; i < 4; ++i)
#pragma unroll
    for (int j = 0; j < 4; ++j) acc[i][j] = (f32x4){0.f, 0.f, 0.f, 0.f};

  int aoff[4], boff[4];
  const int cl = lane >> 4;
#pragma unroll
  for (int r = 0; r < 4; ++r) {
    int rowa = wm * 64 + r * 16 + (lane & 15);
    aoff[r] = rowa * 32 + (cl ^ ((rowa >> 1) & 3)) * 8;
    int rowb = wn * 64 + r * 16 + (lane & 15);
    boff[r] = rowb * 32 + (cl ^ ((rowb >> 1) & 3)) * 8;
  }
  int srow[2], scg[2];
#pragma unroll
  for (int it = 0; it < 2; ++it) {
    int ch = wave * 64 + it * 256 + lane;
    srow[it] = ch >> 2;
    scg[it]  = (ch & 3) ^ ((srow[it] >> 1) & 3);
  }

#define STAGE(bf_, k0_)                                                        \
  do {                                                                         \
    _Pragma("unroll")                                                          \
    for (int it = 0; it < 2; ++it) {                                           \
      gld_lds16(A + (size_t)(m0 + srow[it]) * (size_t)lda +                    \
                    ((k0_) + scg[it] * 8),                                     \
                &ldsA[bf_][(wave * 64 + it * 256) * 8]);                       \
      gld_lds16(B + (size_t)(n0 + srow[it]) * (size_t)ldb +                    \
                    ((k0_) + scg[it] * 8),                                     \
                &ldsB[bf_][(wave * 64 + it * 256) * 8]);                       \
    }                                                                          \
  } while (0)

  const int Kc   = K / ksplit;
  const int kbeg = ks * Kc;
  const int nt   = Kc / 32;

  STAGE(0, kbeg);
  for (int t = 0; t < nt; ++t) {
    const int cur = t & 1;
    if (t + 1 < nt) {
      STAGE(cur ^ 1, kbeg + (t + 1) * 32);
      asm volatile("s_waitcnt vmcnt(4)" ::: "memory");
    } else {
      asm volatile("s_waitcnt vmcnt(0)" ::: "memory");
    }
    __builtin_amdgcn_s_barrier();
    __builtin_amdgcn_sched_barrier(0);
    f16x8 af[4], bf[4];
#pragma unroll
    for (int r = 0; r < 4; ++r) af[r] = *(const f16x8*)&ldsA[cur][aoff[r]];
#pragma unroll
    for (int r = 0; r < 4; ++r) bf[r] = *(const f16x8*)&ldsB[cur][boff[r]];
#pragma unroll
    for (int mr = 0; mr < 4; ++mr)
#pragma unroll
      for (int nr = 0; nr < 4; ++nr)
        acc[mr][nr] = __builtin_amdgcn_mfma_f32_16x16x32_f16(
            af[mr], bf[nr], acc[mr][nr], 0, 0, 0);
    __builtin_amdgcn_sched_barrier(0);
    __builtin_amdgcn_s_barrier();
    __builtin_amdgcn_sched_barrier(0);
  }
#undef STAGE

  const size_t cz = (ksplit > 1) ? (size_t)blockIdx.z : (size_t)zb;
  float* c32 = C32 ? C32 + cz * (size_t)sCb : nullptr;
  f16*   c16 = C16 ? C16 + cz * (size_t)sCb : nullptr;
#pragma unroll
  for (int mr = 0; mr < 4; ++mr) {
#pragma unroll
    for (int r = 0; r < 4; ++r) {
      int grow = m0 + wm * 64 + mr * 16 + (lane >> 4) * 4 + r;
      float brv = bias_row ? bias_row[grow] : 0.f;
#pragma unroll
      for (int nr = 0; nr < 4; ++nr) {
        int gcol = n0 + wn * 64 + nr * 16 + (lane & 15);
        float v = acc[mr][nr][r] * scale + brv +
                  (bias_col ? bias_col[gcol] : 0.f);
        if (c32) c32[(size_t)grow * N + gcol] = v;
        else     c16[(size_t)grow * N + gcol] = (f16)v;
      }
    }
  }
}

// ---------------- fused-P GEMM v4: BARRIER-FREE, B direct from L2 ----------
// Each wave autonomous: 64m x 128n, acc[4][8]. B fragments loaded straight
// from textT (L2-resident, one batch per XCD via swizzle) as per-lane 16B
// contiguous loads in exact MFMA fragment layout. A synthesized in-register
// (P[i,k] = exp2(u_i*cA2[k]+cB2[k]) * inv2_i); the ~130 VALU inst of
// synthesis cover the B-load L2 latency. No s_barrier in the K-loop, LDS
// only 8 KB consts. Split-K=4, f16 partials. Grid 512, 2 waves/SIMD.
__global__ __launch_bounds__(256, 2) void gemm_pt(
    const f16* __restrict__ Bt, const float* __restrict__ uarr,
    const float* __restrict__ inv2, const float* __restrict__ Acs,
    const float* __restrict__ bb2s, f16* __restrict__ parts)
{
  __shared__ float cA2[1024], cB2[1024];   // consts * log2(e)
  const int tid  = threadIdx.x;
  const int lane = tid & 63;
  const int wave = tid >> 6;
  // swizzle: 512 blocks -> 64 contiguous per XCD = one batch
  int id = (int)blockIdx.x;
  id = (id & 7) * 64 + (id >> 3);
  const int zb  = id >> 6;
  const int rem = id & 63;
  const int mt  = rem >> 2;                // 16 m-tiles of 64 rows
  const int ks  = rem & 3;                 // 4 K-chunks of 1024
  const int kbeg = ks * 1024;
  const int m0 = mt * 64;
  const int n0 = wave * 128;               // wave owns 128 of D=512
  const f16* B = Bt + (size_t)zb * ((size_t)D_ * S_);

  const float L2E = 1.44269504088896340736f;
  for (int i = tid; i < 1024; i += 256) {
    cA2[i] = Acs[kbeg + i] * L2E;
    cB2[i] = bb2s[kbeg + i] * L2E;
  }
  const int kl0 = (lane >> 4) * 8;         // k-slice within a 32-step
  float u_[4], iv_[4];
#pragma unroll
  for (int r = 0; r < 4; ++r) {
    int row = zb * IB_ + m0 + r * 16 + (lane & 15);
    u_[r]  = uarr[row];
    iv_[r] = inv2[row];
  }
  const f16* brow[8];
#pragma unroll
  for (int nr = 0; nr < 8; ++nr)
    brow[nr] = B + (size_t)(n0 + nr * 16 + (lane & 15)) * (size_t)S_ +
               kbeg + kl0;
  f32x4 acc[4][8];
#pragma unroll
  for (int i = 0; i < 4; ++i)
#pragma unroll
    for (int j = 0; j < 8; ++j) acc[i][j] = (f32x4){0.f, 0.f, 0.f, 0.f};
  __syncthreads();                         // consts ready (only barrier)

  for (int t = 0; t < 32; ++t) {
    f16x8 bf[8];
#pragma unroll
    for (int nr = 0; nr < 8; ++nr)
      bf[nr] = *(const f16x8*)(brow[nr] + t * 32);
    const int kk = t * 32 + kl0;
    float a8[8], b8[8];
#pragma unroll
    for (int j = 0; j < 8; ++j) { a8[j] = cA2[kk + j]; b8[j] = cB2[kk + j]; }
    f16x8 af[4];
#pragma unroll
    for (int r = 0; r < 4; ++r)
#pragma unroll
      for (int j = 0; j < 8; ++j)
        af[r][j] = (f16)(exp2f(fmaf(u_[r], a8[j], b8[j])) * iv_[r]);
#pragma unroll
    for (int mr = 0; mr < 4; ++mr)
#pragma unroll
      for (int nr = 0; nr < 8; ++nr)
        acc[mr][nr] = __builtin_amdgcn_mfma_f32_16x16x32_f16(
            af[mr], bf[nr], acc[mr][nr], 0, 0, 0);
  }

  f16* cp = parts + (size_t)(zb * 4 + ks) * (size_t)(IB_ * D_);
#pragma unroll
  for (int mr = 0; mr < 4; ++mr) {
#pragma unroll
    for (int rr = 0; rr < 4; ++rr) {
      int grow = m0 + mr * 16 + (lane >> 4) * 4 + rr;
#pragma unroll
      for (int nr = 0; nr < 8; ++nr) {
        int gcol = n0 + nr * 16 + (lane & 15);
        cp[(size_t)grow * D_ + gcol] = (f16)acc[mr][nr][rr];
      }
    }
  }
}

// ---------------- reduce 4 f16 split-K slices: [B][4][ID] -> [B][ID] ------
__global__ __launch_bounds__(256) void reduce_ks4_f16(
    const f16x8* __restrict__ p, f16x8* __restrict__ o, unsigned n8)
{
  const unsigned pb8 = (IB_ * D_) / 8;   // 65536 f16x8 units per slice
  unsigned i = blockIdx.x * 256u + threadIdx.x;
  const unsigned stride = gridDim.x * 256u;
  for (; i < n8; i += stride) {
    unsigned g = i / pb8, r = i - g * pb8;
    size_t base = ((size_t)g * 4u) * pb8 + r;
    float acc[8] = {0.f, 0.f, 0.f, 0.f, 0.f, 0.f, 0.f, 0.f};
#pragma unroll
    for (int ks = 0; ks < 4; ++ks) {
      f16x8 v = p[base + (size_t)ks * pb8];
#pragma unroll
      for (int j = 0; j < 8; ++j) acc[j] += (float)v[j];
    }
    f16x8 h;
#pragma unroll
    for (int j = 0; j < 8; ++j) h[j] = (f16)acc[j];
    o[i] = h;
  }
}

// ---------------- reduce 2 f16 slices + col bias -> f32 out ---------------
__global__ __launch_bounds__(256) void reduce_ks2_bias(
    const f16x8* __restrict__ p, const float* __restrict__ bias,
    float4* __restrict__ o, unsigned n8)
{
  unsigned i = blockIdx.x * 256u + threadIdx.x;
  const unsigned stride = gridDim.x * 256u;
  for (; i < n8; i += stride) {
    f16x8 a = p[i];
    f16x8 b = p[i + (size_t)n8];
    const int c0 = (int)((i * 8u) & (D_ - 1));
    float4 lo, hi;
    lo.x = (float)a[0] + (float)b[0] + bias[c0 + 0];
    lo.y = (float)a[1] + (float)b[1] + bias[c0 + 1];
    lo.z = (float)a[2] + (float)b[2] + bias[c0 + 2];
    lo.w = (float)a[3] + (float)b[3] + bias[c0 + 3];
    hi.x = (float)a[4] + (float)b[4] + bias[c0 + 4];
    hi.y = (float)a[5] + (float)b[5] + bias[c0 + 5];
    hi.z = (float)a[6] + (float)b[6] + bias[c0 + 6];
    hi.w = (float)a[7] + (float)b[7] + bias[c0 + 7];
    o[(size_t)i * 2]     = lo;
    o[(size_t)i * 2 + 1] = hi;
  }
}

// ---------------- f32 -> f16 ----------------
__global__ __launch_bounds__(256) void cvt_f32_to_f16(
    const float* __restrict__ in, f16* __restrict__ out, unsigned n)
{
  unsigned i = (blockIdx.x * 256u + threadIdx.x) * 4u;
  if (i >= n) return;
  const float4 v = *(const float4*)(in + i);
  f16x4 h;
  h[0] = (f16)v.x; h[1] = (f16)v.y; h[2] = (f16)v.z; h[3] = (f16)v.w;
  *(f16x4*)(out + i) = h;
}

// ---- fused: text (B,S,D) f32 -> textT (B,D,S) f16  +  muk-weighted
//      partial row-sums tp[b][s0/64][d] (uses the tile already in LDS) -----
__global__ __launch_bounds__(256) void transpose_text_fused(
    const float* __restrict__ in, const float* __restrict__ muk,
    f16* __restrict__ out, float* __restrict__ tp)
{
  __shared__ float t[32][65];
  __shared__ float muks[64];
  __shared__ float red[8][32];
  const int b = blockIdx.z;
  const int s0 = blockIdx.x * 64, d0 = blockIdx.y * 32;
  const int tid = threadIdx.x;
  const int dx = tid & 31;
  const int sy = tid >> 5;
  const float* ip = in + ((size_t)b * S_ + s0) * D_ + d0;
  if (tid < 64) muks[tid] = muk[s0 + tid];
#pragma unroll
  for (int j = 0; j < 8; ++j) {
    int sl = j * 8 + sy;
    t[dx][sl] = ip[(size_t)sl * D_ + dx];
  }
  __syncthreads();
  const int sx = tid & 63;
  const int dy = tid >> 6;
  f16* op = out + ((size_t)b * D_ + d0) * S_ + s0;
#pragma unroll
  for (int j = 0; j < 8; ++j) {
    int dl = j * 4 + dy;
    op[(size_t)dl * S_ + sx] = (f16)t[dl][sx];
  }
  // weighted partial sums over the 64 s-rows of this tile
  float ps = 0.f;
#pragma unroll
  for (int i = 0; i < 8; ++i) {
    int sl = sy * 8 + i;
    ps += muks[sl] * t[dx][sl];
  }
  red[sy][dx] = ps;
  __syncthreads();
  if (tid < 32) {
    float a = 0.f;
#pragma unroll
    for (int g = 0; g < 8; ++g) a += red[g][tid];
    tp[((size_t)b * 64 + (s0 >> 6)) * D_ + d0 + tid] = a;
  }
}

// ---------------- row sums of Wb2s (S, IB): Acs[s] = sum_j W[s,j] --------
__global__ __launch_bounds__(256) void rowsum_kernel(
    const float* __restrict__ W, float* __restrict__ out)
{
  int s = blockIdx.x;
  const float* row = W + (size_t)s * IB_;
  float acc = 0.f;
  for (int j = threadIdx.x; j < IB_; j += 256) acc += row[j];
  __shared__ float red[4];
#pragma unroll
  for (int o = 32; o >= 1; o >>= 1) acc += __shfl_xor(acc, o);
  if ((threadIdx.x & 63) == 0) red[threadIdx.x >> 6] = acc;
  __syncthreads();
  if (threadIdx.x == 0) out[s] = red[0] + red[1] + red[2] + red[3];
}

// ---------------- mu = alpha*Acs + bb2s, top-2050 mask, r̂ -----------------
__device__ __forceinline__ unsigned fkey(float x) {
  unsigned u = __float_as_uint(x);
  return (u & 0x80000000u) ? ~u : (u | 0x80000000u);
}

__global__ __launch_bounds__(256) void prep_mu(
    const float* __restrict__ Acs, const float* __restrict__ bb2s,
    float* __restrict__ muk, float* __restrict__ rhat)
{
  __shared__ float vals[S_];
  __shared__ unsigned hist[256];
  __shared__ unsigned sprefix;
  __shared__ int srem;
  __shared__ float rred[4];
  const float e1 = 2.71828182845904523536f;
  const float Z = 3.f * e1 + (float)(IB_ - 3);   // interior-row normalizer
  const float alpha = 1.f / Z;
  for (int s = threadIdx.x; s < S_; s += 256)
    vals[s] = alpha * Acs[s] + bb2s[s];
  if (threadIdx.x == 0) { sprefix = 0u; srem = S_ / 2 + 2; }  // 2050
  __syncthreads();
  for (int shift = 24; shift >= 0; shift -= 8) {
    hist[threadIdx.x] = 0u;
    __syncthreads();
    unsigned pfx = sprefix;
    unsigned himask = (shift == 24) ? 0u : (0xFFFFFFFFu << (shift + 8));
    for (int s = threadIdx.x; s < S_; s += 256) {
      unsigned key = fkey(vals[s]);
      if ((key & himask) == (pfx & himask))
        atomicAdd(&hist[(key >> shift) & 255u], 1u);
    }
    __syncthreads();
    if (threadIdx.x == 0) {
      int rem = srem;
      unsigned acc = 0;
      int b = 255;
      for (; b > 0; --b) {
        unsigned c = hist[b];
        if (acc + c >= (unsigned)rem) break;
        acc += c;
      }
      sprefix = pfx | ((unsigned)b << shift);
      srem = rem - (int)acc;
    }
    __syncthreads();
  }
  const unsigned T = sprefix;
  float myrs = 0.f;
  for (int s = threadIdx.x; s < S_; s += 256) {
    float v = vals[s];
    bool keep = fkey(v) >= T;
    muk[s] = keep ? v : 0.f;
    if (keep) myrs += v;
  }
#pragma unroll
  for (int o = 32; o >= 1; o >>= 1) myrs += __shfl_xor(myrs, o);
  if ((threadIdx.x & 63) == 0) rred[threadIdx.x >> 6] = myrs;
  __syncthreads();
  if (threadIdx.x == 0) rhat[0] = rred[0] + rred[1] + rred[2] + rred[3];
}

// ---------------- tt[b][d] = sum_c tp[b][c][d], c = 64 chunks ------------
__global__ __launch_bounds__(256) void tt_reduce(
    const float* __restrict__ tp, float* __restrict__ tt)
{
  const int d = blockIdx.x * 256 + threadIdx.x;   // gridDim.x = 2
  const int b = blockIdx.y;                        // gridDim.y = 8
  float acc = 0.f;
#pragma unroll
  for (int c = 0; c < 64; ++c) acc += tp[((size_t)b * 64 + c) * D_ + d];
  tt[(size_t)b * D_ + d] = acc;
}

// ---------------- m̂[b][r] = Wk[r,:].tt[b] + bk[r]*r̂ ; grid = 512 rows ----
__global__ __launch_bounds__(256) void mhat2_kernel(
    const float* __restrict__ tt, const float* __restrict__ Wk,
    const float* __restrict__ bk, const float* __restrict__ rhat,
    float* __restrict__ mh)
{
  __shared__ float tl[B_ * D_];        // 16 KB: all batches' t̂
  const int t = threadIdx.x;
  for (int i = t; i < B_ * D_; i += 256) tl[i] = tt[i];
  __syncthreads();
  const int r = blockIdx.x;
  const int lane = t & 63, wave = t >> 6;
  const float* wr = Wk + (size_t)r * D_;
  float w[8];
#pragma unroll
  for (int j = 0; j < 8; ++j) w[j] = wr[lane + 64 * j];
  const float bkr = bk[r] * rhat[0];
#pragma unroll
  for (int bb = 0; bb < 2; ++bb) {
    const int b = wave * 2 + bb;
    float acc = 0.f;
#pragma unroll
    for (int j = 0; j < 8; ++j) acc += w[j] * tl[b * D_ + lane + 64 * j];
#pragma unroll
    for (int o = 32; o >= 1; o >>= 1) acc += __shfl_xor(acc, o);
    if (lane == 0) mh[b * D_ + r] = acc + bkr;
  }
}

// ---------------- ypart[c][b][d] = sum_{r in chunk c} Wq[r,d]*mh[b][r] ----
__global__ __launch_bounds__(256) void ypart_kernel(
    const float* __restrict__ Wq, const float* __restrict__ mh,
    float* __restrict__ yp)
{
  __shared__ float ms[B_ * 64];        // mh slice: 8 batches x 64 rows
  const int t = threadIdx.x;
  const int d = blockIdx.x * 256 + t;  // gridDim.x = 2
  const int c = blockIdx.y;            // gridDim.y = 8 chunks of 64 rows
  for (int i = t; i < B_ * 64; i += 256) {
    int b = i >> 6, rr = i & 63;
    ms[i] = mh[b * D_ + c * 64 + rr];
  }
  __syncthreads();
  float acc[8] = {0.f, 0.f, 0.f, 0.f, 0.f, 0.f, 0.f, 0.f};
  for (int rr = 0; rr < 64; ++rr) {
    float wv = Wq[(size_t)(c * 64 + rr) * D_ + d];
#pragma unroll
    for (int b = 0; b < 8; ++b) acc[b] += wv * ms[b * 64 + rr];
  }
#pragma unroll
  for (int b = 0; b < 8; ++b)
    yp[((size_t)c * 8 + b) * D_ + d] = acc[b];
}

// ---------------- y[b][d] = sum_c ypart[c][b][d] -------------------------
__global__ __launch_bounds__(256) void yred_kernel(
    const float* __restrict__ yp, float* __restrict__ y)
{
  const int d = blockIdx.x * 256 + threadIdx.x;   // gridDim.x = 2
  const int b = blockIdx.y;                        // gridDim.y = 8
  float acc = 0.f;
#pragma unroll
  for (int c = 0; c < 8; ++c) acc += yp[((size_t)c * 8 + b) * D_ + d];
  y[(size_t)b * D_ + d] = acc;
}

// ---------------- cb[b] = bq . mh[b] -------------------------------------
__global__ __launch_bounds__(256) void cb_kernel(
    const float* __restrict__ bq, const float* __restrict__ mh,
    float* __restrict__ cb)
{
  const int lane = threadIdx.x & 63, wave = threadIdx.x >> 6;
#pragma unroll
  for (int bb = 0; bb < 2; ++bb) {
    const int b = wave * 2 + bb;
    float acc = 0.f;
#pragma unroll
    for (int j = 0; j < 8; ++j) {
      int k = lane + 64 * j;
      acc += bq[k] * mh[b * D_ + k];
    }
#pragma unroll
    for (int o = 32; o >= 1; o >>= 1) acc += __shfl_xor(acc, o);
    if (lane == 0) cb[b] = acc;
  }
}

// ---------------- fused u + softmax stats per row -------------------------
// u[row] = (img_row . y_b + cb[b]) * scl ; inv2[row] = exp(-mx)/Z
__global__ __launch_bounds__(256) void upstat_kernel(
    const float* __restrict__ img, const float* __restrict__ y,
    const float* __restrict__ cbv, const float* __restrict__ Acs,
    const float* __restrict__ bb2s, float scl,
    float* __restrict__ uo, float* __restrict__ inv2)
{
  const int row = blockIdx.x;
  const int b = row >> 10;
  const int t = threadIdx.x;
  __shared__ float red[4];
  __shared__ float ubc;
  const float* ir = img + (size_t)row * D_;
  const float* yb = y + (size_t)b * D_;
  float du = ir[t] * yb[t] + ir[t + 256] * yb[t + 256];
#pragma unroll
  for (int o = 32; o >= 1; o >>= 1) du += __shfl_xor(du, o);
  if ((t & 63) == 0) red[t >> 6] = du;
  __syncthreads();
  if (t == 0) {
    float uu = (red[0] + red[1] + red[2] + red[3] + cbv[b]) * scl;
    ubc = uu;
    uo[row] = uu;
  }
  __syncthreads();
  const float u = ubc;
  float v[16];
  float mx = -3.4e38f;
#pragma unroll
  for (int j = 0; j < 16; ++j) {
    int s = t + 256 * j;
    v[j] = fmaf(u, Acs[s], bb2s[s]);
    mx = fmaxf(mx, v[j]);
  }
#pragma unroll
  for (int o = 32; o >= 1; o >>= 1) mx = fmaxf(mx, __shfl_xor(mx, o));
  if ((t & 63) == 0) red[t >> 6] = mx;
  __syncthreads();
  mx = fmaxf(fmaxf(red[0], red[1]), fmaxf(red[2], red[3]));
  __syncthreads();
  float sum = 0.f;
#pragma unroll
  for (int j = 0; j < 16; ++j) sum += __expf(v[j] - mx);
#pragma unroll
  for (int o = 32; o >= 1; o >>= 1) sum += __shfl_xor(sum, o);
  if ((t & 63) == 0) red[t >> 6] = sum;
  __syncthreads();
  if (t == 0) {
    float Zs = red[0] + red[1] + red[2] + red[3];
    inv2[row] = __expf(-mx) / Zs;
  }
}

// =========================================================================
extern "C" void kernel_launch(void* const* d_in, const int* in_sizes, int n_in,
                              void* d_out, int out_size, void* d_ws, size_t ws_size,
                              hipStream_t stream)
{
  const float* text = (const float*)d_in[0];   // (B,S,D)
  const float* img  = (const float*)d_in[1];   // (B,IB,D)
  const float* Wq   = (const float*)d_in[2];
  const float* bq   = (const float*)d_in[3];
  const float* Wk   = (const float*)d_in[4];
  const float* bk   = (const float*)d_in[5];
  const float* Wv   = (const float*)d_in[6];
  const float* bv   = (const float*)d_in[7];
  const float* Wb2s = (const float*)d_in[8];   // (S,IB)
  const float* bb2s = (const float*)d_in[9];   // (S,)
  float* outp = (float*)d_out;
  char* ws = (char*)d_ws;

  const long long ID = (long long)IB_ * D_;    // 2^19
  const size_t MB = 1048576ull;

  // ws layout (NEED = 96 MiB; >=200 MiB proved available in round 2):
  //  [  0, 32)  textT f16 (B,D,S)
  //  [ 32, 40)  pt16 f16
  //  [ 40, 72)  parts_pt f16, 4 slices x 8 MB
  //  [ 72, 88)  parts_out f16, 2 slices x 8 MB
  //  [ 88, 89)  wv16
  //  [ 89, ..)  smalls
  const size_t NEED = 96 * MB;
  if (ws_size < NEED) return;

  f16*   textT   = (f16*)(ws + 0);
  f16*   pt16    = (f16*)(ws + 32 * MB);
  f16*   partsPT = (f16*)(ws + 40 * MB);
  f16*   partsO  = (f16*)(ws + 72 * MB);
  f16*   wv16    = (f16*)(ws + 88 * MB);
  const size_t SB = 89 * MB;
  float* Acs  = (float*)(ws + SB);
  float* muk  = (float*)(ws + SB + 16384);
  float* tp   = (float*)(ws + SB + 32768);        // 8*64*512*4 = 1 MB
  float* tt   = (float*)(ws + SB + 1081344);
  float* mh   = (float*)(ws + SB + 1097728);
  float* rhat = (float*)(ws + SB + 1114112);
  float* yp   = (float*)(ws + SB + 1118208);      // 128 KB
  float* y    = (float*)(ws + SB + 1249280);
  float* cb   = (float*)(ws + SB + 1265664);
  float* u    = (float*)(ws + SB + 1269760);      // 32 KB
  float* inv2 = (float*)(ws + SB + 1302528);      // 32 KB

  dim3 blk(256);
  const float scl = 0.04419417382415922f;  // 1/sqrt(512)

  // 1) Acs = rowsum(Wb2s); mu + top-2050 mask + r̂
  rowsum_kernel<<<S_, blk, 0, stream>>>(Wb2s, Acs);
  prep_mu<<<1, blk, 0, stream>>>(Acs, bb2s, muk, rhat);
  // 2) textT + muk-weighted partial sums (fused; text read once)
  transpose_text_fused<<<dim3(S_/64, D_/32, B_), blk, 0, stream>>>(
      text, muk, textT, tp);
  tt_reduce<<<dim3(2, B_), blk, 0, stream>>>(tp, tt);
  // 3) m̂_b = Wk @ t̂_b + bk*r̂
  mhat2_kernel<<<512, blk, 0, stream>>>(tt, Wk, bk, rhat, mh);
  // 4) y_b = Wq^T @ m̂_b ; cb_b = bq . m̂_b
  ypart_kernel<<<dim3(2, 8), blk, 0, stream>>>(Wq, mh, yp);
  yred_kernel<<<dim3(2, B_), blk, 0, stream>>>(yp, y);
  cb_kernel<<<1, blk, 0, stream>>>(bq, mh, cb);
  // 5) u + softmax stats fused (P never materialized)
  upstat_kernel<<<B_ * IB_, blk, 0, stream>>>(img, y, cb, Acs, bb2s, scl,
                                              u, inv2);
  // 6) pt_b = P_b @ text_b, barrier-free wave-autonomous GEMM; KS=4
  gemm_pt<<<512, blk, 0, stream>>>(textT, u, inv2, Acs, bb2s, partsPT);
  // 7) reduce 4 slices -> pt16 f16
  reduce_ks4_f16<<<1024, blk, 0, stream>>>(
      (const f16x8*)partsPT, (f16x8*)pt16, (unsigned)((B_ * ID) / 8));
  // 8) Wv -> f16
  cvt_f32_to_f16<<<(D_*D_)/1024, blk, 0, stream>>>(Wv, wv16, D_*D_);
  // 9) out = pt @ Wv^T (+bv at reduce) : split-K=2, f16 partials
  gemm_bt<<<dim3(D_/128, (B_*IB_)/128, 2), blk, 0, stream>>>(
      pt16, wv16, nullptr, partsO, B_*IB_, D_, D_, D_, D_, 2,
      0, 0, (long long)B_ * ID, nullptr, nullptr, 1.f);
  // 10) reduce 2 slices + bv -> d_out f32 (softmax rows sum to 1, so
  //     P @ bv-broadcast == bv exactly)
  reduce_ks2_bias<<<1024, blk, 0, stream>>>(
      (const f16x8*)partsO, bv, (float4*)outp, (unsigned)((B_ * ID) / 8));
}